// Round 13
// baseline (125.979 us; speedup 1.0000x reference)
//
#include <hip/hip_runtime.h>
#include <hip/hip_bf16.h>

// Fused Asterisk block, round 13: r12 schedule, MFMA 16x16x32 -> 32x32x16.
// Per tap: 16 MFMA (2mb x 4nb x 2kh) instead of 32; same acc regs (2x4xf32x16),
// same LDS traffic (8 ds_read_b128/tap), cheaper B addressing (idx00 +nb*1024,
// ^16 per k-half). wp layout unchanged (serves both fragment shapes).
//
// Fragment maps (32x32x16 bf16): A/B lane l: m|n = l&31, k = (l>>5)*8 + j
// (+kh*16). C/D (guide-verified m74/m101): col = l&31,
// row = (rr&3) + 8*(rr>>2) + 4*(l>>5), rr in [0,16).
//
// Tap geometry (verified r0-r12), tap k, staged slot r (row = i0+2r-4):
//   g=0: r=2+l, dj=2k-4 | g=1: r=k+l, dj=0 | g=2: r=k+l, dj=4-2k
//   g=3: r=4-k+l, dj=2k-4      (l = local output row, i = i0+2l)
// LDS swizzle (write and read, verified r2-r12):
//   octet slot = owner ^ ((col>>2)&3); short-index bit5 ^= (col>>4)&1.

typedef __attribute__((ext_vector_type(8))) __bf16 bf16x8;
typedef __attribute__((ext_vector_type(16))) float f32x16;

#define HH 128
#define WW 128
#define CIN 256
#define NCHUNK 8
#define CHUNK 32
#define COLS 136
#define TROWS 6
#define BUF_SHORTS (TROWS*COLS*CHUNK)   // 26112 shorts; dbuf = 104448 B
#define WPG (40*64*32)                  // 81920 bf16 per branch

__device__ __forceinline__ ushort f2bf(float f) {
    union { float f; unsigned u; } v; v.f = f;
    unsigned r = v.u + 0x7FFF + ((v.u >> 16) & 1);   // RNE
    return (ushort)(r >> 16);
}

// wp[((g*40 + s)*64 + m)*32 + kk] = bf16( w_g[(m*256 + (s/5)*32 + kk)*5 + (s%5)] )
__global__ void repack_w(const float* __restrict__ w0, const float* __restrict__ w1,
                         const float* __restrict__ w2, const float* __restrict__ w3,
                         ushort* __restrict__ wp) {
    int idx = blockIdx.x * 256 + threadIdx.x;   // 0..327679
    int g   = idx / WPG;
    int rem = idx - g * WPG;
    int s   = rem >> 11;
    int r2  = rem & 2047;
    int m   = r2 >> 5;
    int kk  = r2 & 31;
    int k   = s % 5;
    int cg  = s / 5;
    const float* w = (g == 0) ? w0 : (g == 1) ? w1 : (g == 2) ? w2 : w3;
    wp[idx] = f2bf(w[(m * CIN + cg * 32 + kk) * 5 + k]);
}

__global__ __launch_bounds__(512, 2)
void asterisk_mfma9(const float* __restrict__ x,
                    const ushort* __restrict__ wp,
                    const float* __restrict__ b0, const float* __restrict__ b1,
                    const float* __restrict__ b2, const float* __restrict__ b3,
                    float* __restrict__ out) {
    __shared__ __align__(16) short xs[2][BUF_SHORTS];

    const int t    = threadIdx.x;
    const int lane = t & 63;
    const int wid  = t >> 6;        // 0..7
    const int g    = wid & 3;       // branch
    const int l    = wid >> 2;      // local output row 0/1
    const int l31  = lane & 31;
    const int o5   = lane >> 5;     // k-octet half

    // one batch per XCD (512 blocks round-robin over 8 XCDs)
    const int id = blockIdx.x;
    const int b  = id & 7;
    const int p  = id >> 3;                  // 0..63
    const int i0 = 4 * (p >> 1) + (p & 1);   // block covers rows {i0, i0+2}
    const int i  = i0 + 2 * l;               // this wave's output row

    // ---- zero pad columns in BOTH buffers (cols 0..3, 132..135); persists ----
    for (int e = t; e < 2 * TROWS * 8 * CHUNK; e += 512) {
        int s    = e;
        int bufi = s >= TROWS * 8 * CHUNK;
        if (bufi) s -= TROWS * 8 * CHUNK;
        int r  = s >> 8;
        int pc = (s >> 5) & 7;
        int c  = s & 31;
        int col = (pc < 4) ? pc : 128 + pc;
        xs[bufi][(r * COLS + col) * CHUNK + c] = 0;
    }

    // ---- accumulators init = bias (wave tile M=64 x N=128; 32x32 C layout) ----
    const float* bias = (g == 0) ? b0 : (g == 1) ? b1 : (g == 2) ? b2 : b3;
    f32x16 acc[2][4];
#pragma unroll
    for (int mb = 0; mb < 2; ++mb) {
        f32x16 bv;
#pragma unroll
        for (int rr = 0; rr < 16; ++rr)
            bv[rr] = bias[mb * 32 + (rr & 3) + 8 * (rr >> 2) + 4 * o5];
#pragma unroll
        for (int nb = 0; nb < 4; ++nb) acc[mb][nb] = bv;
    }

    // ---- stage-thread mapping: (rh, cg, q) ----
    const int rh = t >> 8;          // 0/1 -> rows rh*3..rh*3+2
    const int cg = (t >> 5) & 7;    // channel quad within chunk
    const int q  = t & 31;          // col quad: cols 4q..4q+3
    const float* xb = x + (size_t)b * CIN * HH * WW;

    bool rowok[3];
    const float* rowp[3];
#pragma unroll
    for (int r2 = 0; r2 < 3; ++r2) {
        int r   = rh * 3 + r2;
        int row = i0 + 2 * r - 4;
        rowok[r2] = (unsigned)row < HH;
        rowp[r2]  = xb + (size_t)(cg * 4) * (HH * WW)
                       + (size_t)(rowok[r2] ? row : 0) * WW + q * 4;
    }

    float4 st[3][4];   // staged fp32: [local row][channel] x 4 cols = 48 VGPRs

    auto loadchunk = [&](int cc) {
        size_t coff = (size_t)cc * CHUNK * (HH * WW);
#pragma unroll
        for (int r2 = 0; r2 < 3; ++r2) {
            if (rowok[r2]) {
                const float* src = rowp[r2] + coff;
                st[r2][0] = *(const float4*)(src);
                st[r2][1] = *(const float4*)(src + HH * WW);
                st[r2][2] = *(const float4*)(src + 2 * (HH * WW));
                st[r2][3] = *(const float4*)(src + 3 * (HH * WW));
            } else {
                float4 z = {0.f, 0.f, 0.f, 0.f};
                st[r2][0] = z; st[r2][1] = z; st[r2][2] = z; st[r2][3] = z;
            }
        }
    };

    auto writechunk = [&](int sel) {
        int slot = cg >> 1;              // owning octet
        int sub  = (cg & 1) * 4;         // 4-short half of octet
#pragma unroll
        for (int r2 = 0; r2 < 3; ++r2) {
            int r = rh * 3 + r2;
#pragma unroll
            for (int jj = 0; jj < 4; ++jj) {
                int col = q * 4 + 4 + jj;                 // padded col
                int sl  = slot ^ ((col >> 2) & 3);        // octet swizzle
                float f0 = ((const float*)&st[r2][0])[jj];
                float f1 = ((const float*)&st[r2][1])[jj];
                float f2 = ((const float*)&st[r2][2])[jj];
                float f3 = ((const float*)&st[r2][3])[jj];
                __hip_bfloat162 lo = __float22bfloat162_rn(make_float2(f0, f1));
                __hip_bfloat162 hi = __float22bfloat162_rn(make_float2(f2, f3));
                uint2 pk;
                pk.x = *(unsigned*)&lo;
                pk.y = *(unsigned*)&hi;
                int wi = (r * COLS + col) * CHUNK + sl * 8 + sub;
                wi ^= ((col >> 4) & 1) << 5;              // bit5 spread
                *(uint2*)&xs[sel][wi] = pk;
            }
        }
    };

    // A-frag lane base: + s*2048 per K-step; (mb,kh): + mb*1024 + kh*16
    const ushort* wl0 = wp + (size_t)g * WPG + l31 * 32 + o5 * 8;

    // ---- prologue: chunk0 -> buf0; issue chunk1 loads ----
    loadchunk(0);
    writechunk(0);          // compiler inserts vmcnt wait on st
    __syncthreads();        // buf0 + pad zeros published
    loadchunk(1);           // flies under chunk0's MFMA phase

    for (int cc = 0; cc < NCHUNK; ++cc) {
        const int sel = cc & 1;
        const short* xsel = xs[sel];

        // ---- compute: 5 taps over this chunk ----
#pragma unroll
        for (int k = 0; k < 5; ++k) {
            const ushort* wk = wl0 + (size_t)(cc * 5 + k) * 2048;
            bf16x8 a00 = *(const bf16x8*)(wk);                 // mb0 kh0
            bf16x8 a01 = *(const bf16x8*)(wk + 16);            // mb0 kh1
            bf16x8 a10 = *(const bf16x8*)(wk + 1024);          // mb1 kh0
            bf16x8 a11 = *(const bf16x8*)(wk + 1024 + 16);     // mb1 kh1

            int rbase = (g == 0) ? 2 : (g == 3 ? 4 - k : k);
            int r  = rbase + l;
            int dj = (g == 1) ? 0 : (g == 2 ? 4 - 2 * k : 2 * k - 4);
            int col0 = dj + 4 + l31;                  // padded col, nb adds 32
            int sl0  = o5 ^ ((col0 >> 2) & 3);        // kh=0 octet = o5
            int idx00 = ((r * COLS + col0) * CHUNK + sl0 * 8)
                        ^ (((col0 >> 4) & 1) << 5);
            // nb: +1024 (slot/bit5 invariant); kh=1: ^16 (octet ^2)

            bf16x8 bf[4][2];
#pragma unroll
            for (int nb = 0; nb < 4; ++nb) {
                bf[nb][0] = *(const bf16x8*)(&xsel[idx00 + nb * 1024]);
                bf[nb][1] = *(const bf16x8*)(&xsel[(idx00 ^ 16) + nb * 1024]);
            }

            __builtin_amdgcn_s_setprio(1);
#pragma unroll
            for (int nb = 0; nb < 4; ++nb) {
                acc[0][nb] = __builtin_amdgcn_mfma_f32_32x32x16_bf16(
                    a00, bf[nb][0], acc[0][nb], 0, 0, 0);
                acc[1][nb] = __builtin_amdgcn_mfma_f32_32x32x16_bf16(
                    a10, bf[nb][0], acc[1][nb], 0, 0, 0);
            }
#pragma unroll
            for (int nb = 0; nb < 4; ++nb) {
                acc[0][nb] = __builtin_amdgcn_mfma_f32_32x32x16_bf16(
                    a01, bf[nb][1], acc[0][nb], 0, 0, 0);
                acc[1][nb] = __builtin_amdgcn_mfma_f32_32x32x16_bf16(
                    a11, bf[nb][1], acc[1][nb], 0, 0, 0);
            }
            __builtin_amdgcn_s_setprio(0);
        }

        // ---- handoff: write staged chunk cc+1, issue loads cc+2, one barrier ----
        if (cc < NCHUNK - 1) {
            writechunk(sel ^ 1);
            if (cc < NCHUNK - 2) loadchunk(cc + 2);
            __syncthreads();
        }
    }

    // ---- epilogue: 32x32 D layout: col = l31 (+nb*32),
    //      row = mb*32 + (rr&3) + 8*(rr>>2) + 4*o5 ----
    size_t obase = (((size_t)b * 256 + g * 64) * HH + i) * WW;
#pragma unroll
    for (int mb = 0; mb < 2; ++mb)
#pragma unroll
        for (int rr = 0; rr < 16; ++rr) {
            int row = mb * 32 + (rr & 3) + 8 * (rr >> 2) + 4 * o5;
            float* op = out + obase + (size_t)row * (HH * WW) + l31;
#pragma unroll
            for (int nb = 0; nb < 4; ++nb)
                op[nb * 32] = acc[mb][nb][rr];
        }
}

extern "C" void kernel_launch(void* const* d_in, const int* in_sizes, int n_in,
                              void* d_out, int out_size, void* d_ws, size_t ws_size,
                              hipStream_t stream) {
    const float* x    = (const float*)d_in[0];
    const float* w_h  = (const float*)d_in[1];
    const float* b_h  = (const float*)d_in[2];
    const float* w_v  = (const float*)d_in[3];
    const float* b_v  = (const float*)d_in[4];
    const float* w_d1 = (const float*)d_in[5];
    const float* b_d1 = (const float*)d_in[6];
    const float* w_d2 = (const float*)d_in[7];
    const float* b_d2 = (const float*)d_in[8];
    float* out = (float*)d_out;
    ushort* wpack = (ushort*)d_ws;   // needs 655,360 B

    repack_w<<<1280, 256, 0, stream>>>(w_h, w_v, w_d1, w_d2, wpack);
    asterisk_mfma9<<<512, 512, 0, stream>>>(x, wpack, b_h, b_v, b_d1, b_d2, out);
}